// Round 1
// baseline (978.752 us; speedup 1.0000x reference)
//
#include <hip/hip_runtime.h>
#include <hip/hip_bf16.h>
#include <math.h>

// ---------------------------------------------------------------------------
// SAINT-style 2-layer graph conv + linear head + log_softmax
// N=100000 nodes, E=1600000 edges, C=64, HID=64, OUT=40  (all f32)
// ---------------------------------------------------------------------------

__global__ __launch_bounds__(256) void k_deg(const int* __restrict__ row,
                                             unsigned* __restrict__ deg, int nE) {
  int i = blockIdx.x * blockDim.x + threadIdx.x;
  int stride = gridDim.x * blockDim.x;
  for (; i < nE; i += stride) atomicAdd(&deg[row[i]], 1u);
}

__global__ __launch_bounds__(256) void k_dis(const unsigned* __restrict__ deg,
                                             float* __restrict__ dis, int n) {
  int i = blockIdx.x * blockDim.x + threadIdx.x;
  if (i < n) {
    unsigned d = deg[i];
    dis[i] = d > 0u ? rsqrtf((float)d) : 0.f;
  }
}

// h[n,:]   = x[n,:] @ W^T  + b    (message transform)
// agg[n,:] = x[n,:] @ Wr^T + br   (root transform; scatter adds on top later)
// Each wave processes one node at a time; lane l owns output feature l.
// Weight rows live in registers (32 float4 = 128 VGPR); x row staged in LDS
// and broadcast-read as float4.
__global__ __launch_bounds__(256) void k_gemm_dual(
    const float* __restrict__ x, const float* __restrict__ W,
    const float* __restrict__ b, const float* __restrict__ Wr,
    const float* __restrict__ br, float* __restrict__ h,
    float* __restrict__ agg, int nNodes, int reluIn)
{
  __shared__ float4 xrow4[4][16];
  const int t = threadIdx.x, wave = t >> 6, lane = t & 63;
  const float4* W4  = (const float4*)W;    // row l = W4[l*16 + i]
  const float4* Wr4 = (const float4*)Wr;
  float4 w4[16], wr4[16];
#pragma unroll
  for (int i = 0; i < 16; ++i) { w4[i] = W4[lane * 16 + i]; wr4[i] = Wr4[lane * 16 + i]; }
  const float bo = b[lane], bro = br[lane];
  float* xs = (float*)&xrow4[wave][0];
  const int gw = blockIdx.x * 4 + wave, nW = gridDim.x * 4;
  for (int n = gw; n < nNodes; n += nW) {
    float xv = x[(size_t)n * 64 + lane];
    if (reluIn) xv = fmaxf(xv, 0.f);
    xs[lane] = xv;                       // same-wave LDS write->read; compiler
                                         // inserts lgkmcnt wait (wave-coherent)
    float ha = bo, aa = bro;
#pragma unroll
    for (int k4 = 0; k4 < 16; ++k4) {
      float4 xk = xrow4[wave][k4];       // broadcast read
      ha += xk.x * w4[k4].x + xk.y * w4[k4].y + xk.z * w4[k4].z + xk.w * w4[k4].w;
      aa += xk.x * wr4[k4].x + xk.y * wr4[k4].y + xk.z * wr4[k4].z + xk.w * wr4[k4].w;
    }
    h[(size_t)n * 64 + lane]   = ha;
    agg[(size_t)n * 64 + lane] = aa;
  }
}

// agg[row[e], l] += dis[row]*dis[col] * h[col[e], l]   — one wave per edge.
__global__ __launch_bounds__(256) void k_scatter(
    const float* __restrict__ h, float* __restrict__ agg,
    const int* __restrict__ row, const int* __restrict__ col,
    const float* __restrict__ dis, int nE)
{
  const int wid = (blockIdx.x * blockDim.x + threadIdx.x) >> 6;
  const int lane = threadIdx.x & 63;
  const int nW = (gridDim.x * blockDim.x) >> 6;
  for (int e = wid; e < nE; e += nW) {
    int r = row[e], c = col[e];
    float w = dis[r] * dis[c];
    float v = w * h[(size_t)c * 64 + lane];
    atomicAdd(&agg[(size_t)r * 64 + lane], v);
  }
}

// out[n,:] = log_softmax( concat(relu(agg1[n]), relu(agg2[n])) @ Wl^T + bl )
// One wave per node; lanes 0..39 own Wl rows (32 float4 = 128 VGPR).
__global__ __launch_bounds__(256) void k_final(
    const float* __restrict__ agg1, const float* __restrict__ agg2,
    const float* __restrict__ Wl, const float* __restrict__ bl,
    float* __restrict__ out, int nNodes)
{
  __shared__ float4 xrow4[4][32];
  const int t = threadIdx.x, wave = t >> 6, lane = t & 63;
  const int lc = lane < 40 ? lane : 0;
  const float4* Wl4 = (const float4*)Wl;   // row l = Wl4[l*32 + i]
  float4 wl4[32];
#pragma unroll
  for (int i = 0; i < 32; ++i) wl4[i] = Wl4[lc * 32 + i];
  const float blv = bl[lc];
  float* xs = (float*)&xrow4[wave][0];
  const int gw = blockIdx.x * 4 + wave, nW = gridDim.x * 4;
  for (int n = gw; n < nNodes; n += nW) {
    xs[lane]      = fmaxf(agg1[(size_t)n * 64 + lane], 0.f);
    xs[64 + lane] = fmaxf(agg2[(size_t)n * 64 + lane], 0.f);
    float acc = blv;
#pragma unroll
    for (int k4 = 0; k4 < 32; ++k4) {
      float4 xk = xrow4[wave][k4];
      acc += xk.x * wl4[k4].x + xk.y * wl4[k4].y + xk.z * wl4[k4].z + xk.w * wl4[k4].w;
    }
    float lv = lane < 40 ? acc : -INFINITY;
    float m = lv;
#pragma unroll
    for (int off = 32; off; off >>= 1) m = fmaxf(m, __shfl_xor(m, off));
    float ex = lane < 40 ? __expf(acc - m) : 0.f;
    float s = ex;
#pragma unroll
    for (int off = 32; off; off >>= 1) s += __shfl_xor(s, off);
    if (lane < 40) out[(size_t)n * 40 + lane] = acc - m - __logf(s);
  }
}

extern "C" void kernel_launch(void* const* d_in, const int* in_sizes, int n_in,
                              void* d_out, int out_size, void* d_ws, size_t ws_size,
                              hipStream_t stream) {
  const float* x0  = (const float*)d_in[0];
  const int*   ei  = (const int*)d_in[1];     // [2][E] flat: row then col
  const float* W1  = (const float*)d_in[2];
  const float* b1  = (const float*)d_in[3];
  const float* Wr1 = (const float*)d_in[4];
  const float* br1 = (const float*)d_in[5];
  const float* W2  = (const float*)d_in[6];
  const float* b2  = (const float*)d_in[7];
  const float* Wr2 = (const float*)d_in[8];
  const float* br2 = (const float*)d_in[9];
  const float* Wl  = (const float*)d_in[10];
  const float* bl  = (const float*)d_in[11];
  float* out = (float*)d_out;

  const int N = in_sizes[0] / 64;
  const int E = in_sizes[1] / 2;
  const int* row = ei;
  const int* col = ei + E;

  // workspace layout (floats): deg[N] | dis[N] | h[64N] | agg1[64N] | agg2[64N]
  float* f = (float*)d_ws;
  unsigned* deg = (unsigned*)f;
  float* dis  = f + (size_t)N;
  float* h    = f + (size_t)2 * N;
  float* agg1 = f + (size_t)2 * N + (size_t)64 * N;
  float* agg2 = f + (size_t)2 * N + (size_t)128 * N;

  hipMemsetAsync(deg, 0, (size_t)N * 4, stream);
  k_deg<<<1024, 256, 0, stream>>>(row, deg, E);
  k_dis<<<(N + 255) / 256, 256, 0, stream>>>(deg, dis, N);

  // layer 1
  k_gemm_dual<<<2048, 256, 0, stream>>>(x0, W1, b1, Wr1, br1, h, agg1, N, 0);
  k_scatter<<<2048, 256, 0, stream>>>(h, agg1, row, col, dis, E);

  // layer 2 (reads relu(agg1) on the fly)
  k_gemm_dual<<<2048, 256, 0, stream>>>(agg1, W2, b2, Wr2, br2, h, agg2, N, 1);
  k_scatter<<<2048, 256, 0, stream>>>(h, agg2, row, col, dis, E);

  // head
  k_final<<<2048, 256, 0, stream>>>(agg1, agg2, Wl, bl, out, N);
}

// Round 2
// 563.186 us; speedup vs baseline: 1.7379x; 1.7379x over previous
//
#include <hip/hip_runtime.h>
#include <hip/hip_bf16.h>
#include <math.h>

// ---------------------------------------------------------------------------
// SAINT-style 2-layer graph conv + linear head + log_softmax
// N=100000 nodes, E=1600000 edges, C=64, HID=64, OUT=40  (all f32)
// Round 1: replace atomic feature-scatter with CSR build + gather segment-sum.
// ---------------------------------------------------------------------------

__global__ __launch_bounds__(256) void k_deg(const int* __restrict__ row,
                                             unsigned* __restrict__ deg, int nE) {
  int i = blockIdx.x * blockDim.x + threadIdx.x;
  int stride = gridDim.x * blockDim.x;
  for (; i < nE; i += stride) atomicAdd(&deg[row[i]], 1u);
}

__global__ __launch_bounds__(256) void k_dis(const unsigned* __restrict__ deg,
                                             float* __restrict__ dis, int n) {
  int i = blockIdx.x * blockDim.x + threadIdx.x;
  if (i < n) {
    unsigned d = deg[i];
    dis[i] = d > 0u ? rsqrtf((float)d) : 0.f;
  }
}

// ---- 3-kernel exclusive scan of deg -> start (2048 elems / block) ----------
__global__ __launch_bounds__(256) void k_scan1(const unsigned* __restrict__ deg,
                                               unsigned* __restrict__ start,
                                               unsigned* __restrict__ bsum, int n) {
  __shared__ unsigned s[256];
  const int base = blockIdx.x * 2048;
  unsigned v[8], tsum = 0;
#pragma unroll
  for (int j = 0; j < 8; ++j) {
    int idx = base + threadIdx.x * 8 + j;
    v[j] = idx < n ? deg[idx] : 0u;
    tsum += v[j];
  }
  s[threadIdx.x] = tsum;
  __syncthreads();
  for (int off = 1; off < 256; off <<= 1) {
    unsigned t = (threadIdx.x >= off) ? s[threadIdx.x - off] : 0u;
    __syncthreads();
    s[threadIdx.x] += t;
    __syncthreads();
  }
  unsigned run = threadIdx.x ? s[threadIdx.x - 1] : 0u;
  if (threadIdx.x == 255) bsum[blockIdx.x] = s[255];
#pragma unroll
  for (int j = 0; j < 8; ++j) {
    int idx = base + threadIdx.x * 8 + j;
    if (idx < n) start[idx] = run;
    run += v[j];
  }
}

__global__ void k_scan2(unsigned* __restrict__ bsum, int nB) {
  if (threadIdx.x == 0 && blockIdx.x == 0) {
    unsigned run = 0;
    for (int b = 0; b < nB; ++b) { unsigned t = bsum[b]; bsum[b] = run; run += t; }
  }
}

__global__ __launch_bounds__(256) void k_scan3(unsigned* __restrict__ start,
                                               const unsigned* __restrict__ bsum, int n) {
  int i = blockIdx.x * blockDim.x + threadIdx.x;
  if (i < n) start[i] += bsum[i >> 11];
}

// counting-sort placement: colS[p] = col, p = start[row]++ (atomic).
// After this kernel, segment n occupies [start[n-1], start[n>=1? n : ...]) —
// i.e. start[n] has become the segment END; segment begin = n ? start[n-1] : 0.
__global__ __launch_bounds__(256) void k_build(const int* __restrict__ row,
                                               const int* __restrict__ col,
                                               unsigned* __restrict__ start,
                                               int* __restrict__ colS, int nE) {
  int i = blockIdx.x * blockDim.x + threadIdx.x;
  int stride = gridDim.x * blockDim.x;
  for (; i < nE; i += stride) {
    int r = row[i];
    unsigned p = atomicAdd(&start[r], 1u);
    colS[p] = col[i];
  }
}

// h[n,:]   = x[n,:] @ W^T  + b
// agg[n,:] = x[n,:] @ Wr^T + br
__global__ __launch_bounds__(256) void k_gemm_dual(
    const float* __restrict__ x, const float* __restrict__ W,
    const float* __restrict__ b, const float* __restrict__ Wr,
    const float* __restrict__ br, float* __restrict__ h,
    float* __restrict__ agg, int nNodes, int reluIn)
{
  __shared__ float4 xrow4[4][16];
  const int t = threadIdx.x, wave = t >> 6, lane = t & 63;
  const float4* W4  = (const float4*)W;
  const float4* Wr4 = (const float4*)Wr;
  float4 w4[16], wr4[16];
#pragma unroll
  for (int i = 0; i < 16; ++i) { w4[i] = W4[lane * 16 + i]; wr4[i] = Wr4[lane * 16 + i]; }
  const float bo = b[lane], bro = br[lane];
  float* xs = (float*)&xrow4[wave][0];
  const int gw = blockIdx.x * 4 + wave, nW = gridDim.x * 4;
  for (int n = gw; n < nNodes; n += nW) {
    float xv = x[(size_t)n * 64 + lane];
    if (reluIn) xv = fmaxf(xv, 0.f);
    xs[lane] = xv;
    float ha = bo, aa = bro;
#pragma unroll
    for (int k4 = 0; k4 < 16; ++k4) {
      float4 xk = xrow4[wave][k4];
      ha += xk.x * w4[k4].x + xk.y * w4[k4].y + xk.z * w4[k4].z + xk.w * w4[k4].w;
      aa += xk.x * wr4[k4].x + xk.y * wr4[k4].y + xk.z * wr4[k4].z + xk.w * wr4[k4].w;
    }
    h[(size_t)n * 64 + lane]   = ha;
    agg[(size_t)n * 64 + lane] = aa;
  }
}

// agg[n,:] += dis[n] * sum_{e in seg(n)} dis[colS[e]] * h[colS[e],:]
// one wave per node; lane = feature.
__global__ __launch_bounds__(256) void k_spmm(
    const float* __restrict__ h, float* __restrict__ agg,
    const int* __restrict__ colS, const unsigned* __restrict__ startEnd,
    const float* __restrict__ dis, int nNodes)
{
  const int t = threadIdx.x, wave = t >> 6, lane = t & 63;
  const int n = blockIdx.x * 4 + wave;
  if (n >= nNodes) return;
  const unsigned lo = n ? startEnd[n - 1] : 0u;
  const unsigned hi = startEnd[n];
  float m = 0.f;
  for (unsigned base = lo; base < hi; base += 64) {
    const int cnt = (int)min(64u, hi - base);
    int   myc = (lane < cnt) ? colS[base + lane] : 0;
    float myw = (lane < cnt) ? dis[myc] : 0.f;
    int j = 0;
    for (; j + 3 < cnt; j += 4) {
      int c0 = __shfl(myc, j), c1 = __shfl(myc, j + 1);
      int c2 = __shfl(myc, j + 2), c3 = __shfl(myc, j + 3);
      float w0 = __shfl(myw, j), w1 = __shfl(myw, j + 1);
      float w2 = __shfl(myw, j + 2), w3 = __shfl(myw, j + 3);
      float v0 = h[(size_t)c0 * 64 + lane];
      float v1 = h[(size_t)c1 * 64 + lane];
      float v2 = h[(size_t)c2 * 64 + lane];
      float v3 = h[(size_t)c3 * 64 + lane];
      m += w0 * v0; m += w1 * v1; m += w2 * v2; m += w3 * v3;
    }
    for (; j < cnt; ++j) {
      int c = __shfl(myc, j);
      float w = __shfl(myw, j);
      m += w * h[(size_t)c * 64 + lane];
    }
  }
  const size_t o = (size_t)n * 64 + lane;
  agg[o] += dis[n] * m;
}

// legacy atomic scatter (fallback when ws is too small for CSR arrays)
__global__ __launch_bounds__(256) void k_scatter(
    const float* __restrict__ h, float* __restrict__ agg,
    const int* __restrict__ row, const int* __restrict__ col,
    const float* __restrict__ dis, int nE)
{
  const int wid = (blockIdx.x * blockDim.x + threadIdx.x) >> 6;
  const int lane = threadIdx.x & 63;
  const int nW = (gridDim.x * blockDim.x) >> 6;
  for (int e = wid; e < nE; e += nW) {
    int r = row[e], c = col[e];
    float w = dis[r] * dis[c];
    float v = w * h[(size_t)c * 64 + lane];
    atomicAdd(&agg[(size_t)r * 64 + lane], v);
  }
}

__global__ __launch_bounds__(256) void k_final(
    const float* __restrict__ agg1, const float* __restrict__ agg2,
    const float* __restrict__ Wl, const float* __restrict__ bl,
    float* __restrict__ out, int nNodes)
{
  __shared__ float4 xrow4[4][32];
  const int t = threadIdx.x, wave = t >> 6, lane = t & 63;
  const int lc = lane < 40 ? lane : 0;
  const float4* Wl4 = (const float4*)Wl;
  float4 wl4[32];
#pragma unroll
  for (int i = 0; i < 32; ++i) wl4[i] = Wl4[lc * 32 + i];
  const float blv = bl[lc];
  float* xs = (float*)&xrow4[wave][0];
  const int gw = blockIdx.x * 4 + wave, nW = gridDim.x * 4;
  for (int n = gw; n < nNodes; n += nW) {
    xs[lane]      = fmaxf(agg1[(size_t)n * 64 + lane], 0.f);
    xs[64 + lane] = fmaxf(agg2[(size_t)n * 64 + lane], 0.f);
    float acc = blv;
#pragma unroll
    for (int k4 = 0; k4 < 32; ++k4) {
      float4 xk = xrow4[wave][k4];
      acc += xk.x * wl4[k4].x + xk.y * wl4[k4].y + xk.z * wl4[k4].z + xk.w * wl4[k4].w;
    }
    float lv = lane < 40 ? acc : -INFINITY;
    float m = lv;
#pragma unroll
    for (int off = 32; off; off >>= 1) m = fmaxf(m, __shfl_xor(m, off));
    float ex = lane < 40 ? __expf(acc - m) : 0.f;
    float s = ex;
#pragma unroll
    for (int off = 32; off; off >>= 1) s += __shfl_xor(s, off);
    if (lane < 40) out[(size_t)n * 40 + lane] = acc - m - __logf(s);
  }
}

extern "C" void kernel_launch(void* const* d_in, const int* in_sizes, int n_in,
                              void* d_out, int out_size, void* d_ws, size_t ws_size,
                              hipStream_t stream) {
  const float* x0  = (const float*)d_in[0];
  const int*   ei  = (const int*)d_in[1];
  const float* W1  = (const float*)d_in[2];
  const float* b1  = (const float*)d_in[3];
  const float* Wr1 = (const float*)d_in[4];
  const float* br1 = (const float*)d_in[5];
  const float* W2  = (const float*)d_in[6];
  const float* b2  = (const float*)d_in[7];
  const float* Wr2 = (const float*)d_in[8];
  const float* br2 = (const float*)d_in[9];
  const float* Wl  = (const float*)d_in[10];
  const float* bl  = (const float*)d_in[11];
  float* out = (float*)d_out;

  const int N = in_sizes[0] / 64;
  const int E = in_sizes[1] / 2;
  const int* row = ei;
  const int* col = ei + E;

  // CSR layout (4B words): deg[N] | start[N] | dis[N] | bsum[64] | colS[E] | h | agg1 | agg2
  const size_t needCSR = (size_t)4 * ((size_t)3 * N + 64 + (size_t)E + (size_t)192 * N);

  if (ws_size >= needCSR) {
    unsigned* deg   = (unsigned*)d_ws;
    unsigned* start = deg + N;
    float*    dis   = (float*)(start + N);
    unsigned* bsum  = (unsigned*)(dis + N);
    int*      colS  = (int*)(bsum + 64);
    float*    h     = (float*)(colS + E);
    float*    agg1  = h + (size_t)64 * N;
    float*    agg2  = agg1 + (size_t)64 * N;

    const int nB = (N + 2047) / 2048;

    hipMemsetAsync(deg, 0, (size_t)N * 4, stream);
    k_deg<<<1024, 256, 0, stream>>>(row, deg, E);
    k_dis<<<(N + 255) / 256, 256, 0, stream>>>(deg, dis, N);
    k_scan1<<<nB, 256, 0, stream>>>(deg, start, bsum, N);
    k_scan2<<<1, 64, 0, stream>>>(bsum, nB);
    k_scan3<<<(N + 255) / 256, 256, 0, stream>>>(start, bsum, N);
    k_build<<<1024, 256, 0, stream>>>(row, col, start, colS, E);

    k_gemm_dual<<<2048, 256, 0, stream>>>(x0, W1, b1, Wr1, br1, h, agg1, N, 0);
    k_spmm<<<(N + 3) / 4, 256, 0, stream>>>(h, agg1, colS, start, dis, N);

    k_gemm_dual<<<2048, 256, 0, stream>>>(agg1, W2, b2, Wr2, br2, h, agg2, N, 1);
    k_spmm<<<(N + 3) / 4, 256, 0, stream>>>(h, agg2, colS, start, dis, N);

    k_final<<<2048, 256, 0, stream>>>(agg1, agg2, Wl, bl, out, N);
  } else {
    // fallback: round-0 atomic path
    float* f = (float*)d_ws;
    unsigned* deg = (unsigned*)f;
    float* dis  = f + (size_t)N;
    float* h    = f + (size_t)2 * N;
    float* agg1 = f + (size_t)2 * N + (size_t)64 * N;
    float* agg2 = f + (size_t)2 * N + (size_t)128 * N;

    hipMemsetAsync(deg, 0, (size_t)N * 4, stream);
    k_deg<<<1024, 256, 0, stream>>>(row, deg, E);
    k_dis<<<(N + 255) / 256, 256, 0, stream>>>(deg, dis, N);

    k_gemm_dual<<<2048, 256, 0, stream>>>(x0, W1, b1, Wr1, br1, h, agg1, N, 0);
    k_scatter<<<2048, 256, 0, stream>>>(h, agg1, row, col, dis, E);

    k_gemm_dual<<<2048, 256, 0, stream>>>(agg1, W2, b2, Wr2, br2, h, agg2, N, 1);
    k_scatter<<<2048, 256, 0, stream>>>(h, agg2, row, col, dis, E);

    k_final<<<2048, 256, 0, stream>>>(agg1, agg2, Wl, bl, out, N);
  }
}

// Round 3
// 442.090 us; speedup vs baseline: 2.2139x; 1.2739x over previous
//
#include <hip/hip_runtime.h>
#include <hip/hip_bf16.h>
#include <math.h>

// ---------------------------------------------------------------------------
// SAINT-style 2-layer graph conv + linear head + log_softmax
// N=100000 nodes, E=1600000 edges, C=64, HID=64, OUT=40  (all f32)
// Round 2: replace {deg, scan, build-scatter} with 2-level LDS-staged binning
//          (k_binA bucket sort -> k_binB per-bucket local CSR, coalesced out).
// ---------------------------------------------------------------------------

#define BROWS 512          // rows per bucket (local row fits 9 bits)
#define BIN_CHUNK 8192     // edges per k_binA block

// ---- pass A: bin edges into NB bucket regions, packed (lrow<<17)|col -------
__global__ __launch_bounds__(256) void k_binA(
    const int* __restrict__ row, const int* __restrict__ col,
    unsigned* __restrict__ bCnt, unsigned* __restrict__ pairs,
    int nE, int NB, int capA)
{
  __shared__ unsigned cnt[256], base[256], gb[256], sc[256];
  __shared__ unsigned buf[BIN_CHUNK];
  const int t = threadIdx.x;
  const int tb = blockIdx.x * BIN_CHUNK;

  cnt[t] = 0;
  __syncthreads();

  unsigned pk[32];
  unsigned short po[32];
  short bk[32];
#pragma unroll
  for (int j = 0; j < 32; ++j) {
    int i = tb + j * 256 + t;
    if (i < nE) {
      int r = row[i], c = col[i];
      int b = r >> 9;
      pk[j] = ((unsigned)(r & (BROWS - 1)) << 17) | (unsigned)c;
      bk[j] = (short)b;
      po[j] = (unsigned short)atomicAdd(&cnt[b], 1u);
    } else bk[j] = -1;
  }
  __syncthreads();
  // exclusive scan cnt -> base (NB <= 256)
  sc[t] = cnt[t];
  __syncthreads();
  for (int off = 1; off < 256; off <<= 1) {
    unsigned v = (t >= off) ? sc[t - off] : 0u;
    __syncthreads();
    sc[t] += v;
    __syncthreads();
  }
  base[t] = t ? sc[t - 1] : 0u;
  __syncthreads();
  // ordered place into LDS
#pragma unroll
  for (int j = 0; j < 32; ++j)
    if (bk[j] >= 0) buf[base[bk[j]] + po[j]] = pk[j];
  // reserve global space per bucket
  unsigned c = cnt[t];
  gb[t] = c ? atomicAdd(&bCnt[t], c) : 0u;
  __syncthreads();
  // flush contiguous runs (write-combining friendly)
  for (int b = 0; b < NB; ++b) {
    unsigned cb = cnt[b];
    if (!cb) continue;
    unsigned lo = base[b], g = gb[b];
    size_t dst = (size_t)b * (unsigned)capA;
    for (unsigned u = t; u < cb; u += 256)
      if (g + u < (unsigned)capA) pairs[dst + g + u] = buf[lo + u];
  }
}

// ---- tiny scan of bucket counts -> bucket bases ----------------------------
__global__ __launch_bounds__(256) void k_bscan(const unsigned* __restrict__ bCnt,
                                               unsigned* __restrict__ bBase,
                                               int NB, int capA) {
  __shared__ unsigned sc[256];
  int t = threadIdx.x;
  unsigned v = (t < NB) ? min(bCnt[t], (unsigned)capA) : 0u;
  sc[t] = v;
  __syncthreads();
  for (int off = 1; off < 256; off <<= 1) {
    unsigned u = (t >= off) ? sc[t - off] : 0u;
    __syncthreads();
    sc[t] += u;
    __syncthreads();
  }
  if (t < NB) bBase[t] = t ? sc[t - 1] : 0u;
}

// ---- pass B: per-bucket local CSR in LDS; coalesced colS/start/dis out -----
__global__ __launch_bounds__(256) void k_binB(
    const unsigned* __restrict__ pairs, const unsigned* __restrict__ bCnt,
    const unsigned* __restrict__ bBase, int* __restrict__ colS,
    unsigned* __restrict__ start, float* __restrict__ dis,
    int N, int capA)
{
  __shared__ unsigned hist[BROWS], ex[BROWS], cur[BROWS], sc[256];
  __shared__ unsigned cols[12288];
  const int t = threadIdx.x;
  const int b = blockIdx.x;
  const unsigned cnt = min(bCnt[b], (unsigned)capA);
  const unsigned gbase = bBase[b];
  const size_t src = (size_t)b * (unsigned)capA;

  hist[t] = 0; hist[256 + t] = 0;
  __syncthreads();
  for (unsigned i = t; i < cnt; i += 256)
    atomicAdd(&hist[pairs[src + i] >> 17], 1u);
  __syncthreads();
  // scan hist -> ex (exclusive), 2 elems/thread
  unsigned h0 = hist[2 * t], h1 = hist[2 * t + 1];
  sc[t] = h0 + h1;
  __syncthreads();
  for (int off = 1; off < 256; off <<= 1) {
    unsigned v = (t >= off) ? sc[t - off] : 0u;
    __syncthreads();
    sc[t] += v;
    __syncthreads();
  }
  unsigned bexc = t ? sc[t - 1] : 0u;
  ex[2 * t] = bexc;      cur[2 * t] = bexc;
  ex[2 * t + 1] = bexc + h0; cur[2 * t + 1] = bexc + h0;
  __syncthreads();
  // place cols ordered by local row
  for (unsigned i = t; i < cnt; i += 256) {
    unsigned p = pairs[src + i];
    unsigned pos = atomicAdd(&cur[p >> 17], 1u);
    cols[pos] = p & 0x1FFFFu;
  }
  __syncthreads();
  // coalesced write-out
  for (unsigned i = t; i < cnt; i += 256)
    colS[gbase + i] = (int)cols[i];
  const int rowBase = b * BROWS;
#pragma unroll
  for (int j = 0; j < BROWS / 256; ++j) {
    int lr = j * 256 + t;
    int n = rowBase + lr;
    if (n < N) {
      unsigned d = hist[lr];
      start[n] = gbase + ex[lr] + d;        // segment END offset
      dis[n] = d ? rsqrtf((float)d) : 0.f;
    }
  }
}

// ---------------- fallback-path kernels (round-1 CSR build) -----------------
__global__ __launch_bounds__(256) void k_deg(const int* __restrict__ row,
                                             unsigned* __restrict__ deg, int nE) {
  int i = blockIdx.x * blockDim.x + threadIdx.x;
  int stride = gridDim.x * blockDim.x;
  for (; i < nE; i += stride) atomicAdd(&deg[row[i]], 1u);
}

__global__ __launch_bounds__(256) void k_dis(const unsigned* __restrict__ deg,
                                             float* __restrict__ dis, int n) {
  int i = blockIdx.x * blockDim.x + threadIdx.x;
  if (i < n) {
    unsigned d = deg[i];
    dis[i] = d > 0u ? rsqrtf((float)d) : 0.f;
  }
}

__global__ __launch_bounds__(256) void k_scan1(const unsigned* __restrict__ deg,
                                               unsigned* __restrict__ start,
                                               unsigned* __restrict__ bsum, int n) {
  __shared__ unsigned s[256];
  const int base = blockIdx.x * 2048;
  unsigned v[8], tsum = 0;
#pragma unroll
  for (int j = 0; j < 8; ++j) {
    int idx = base + threadIdx.x * 8 + j;
    v[j] = idx < n ? deg[idx] : 0u;
    tsum += v[j];
  }
  s[threadIdx.x] = tsum;
  __syncthreads();
  for (int off = 1; off < 256; off <<= 1) {
    unsigned t = (threadIdx.x >= off) ? s[threadIdx.x - off] : 0u;
    __syncthreads();
    s[threadIdx.x] += t;
    __syncthreads();
  }
  unsigned run = threadIdx.x ? s[threadIdx.x - 1] : 0u;
  if (threadIdx.x == 255) bsum[blockIdx.x] = s[255];
#pragma unroll
  for (int j = 0; j < 8; ++j) {
    int idx = base + threadIdx.x * 8 + j;
    if (idx < n) start[idx] = run;
    run += v[j];
  }
}

__global__ void k_scan2(unsigned* __restrict__ bsum, int nB) {
  if (threadIdx.x == 0 && blockIdx.x == 0) {
    unsigned run = 0;
    for (int b = 0; b < nB; ++b) { unsigned t = bsum[b]; bsum[b] = run; run += t; }
  }
}

__global__ __launch_bounds__(256) void k_scan3(unsigned* __restrict__ start,
                                               const unsigned* __restrict__ bsum, int n) {
  int i = blockIdx.x * blockDim.x + threadIdx.x;
  if (i < n) start[i] += bsum[i >> 11];
}

__global__ __launch_bounds__(256) void k_build(const int* __restrict__ row,
                                               const int* __restrict__ col,
                                               unsigned* __restrict__ start,
                                               int* __restrict__ colS, int nE) {
  int i = blockIdx.x * blockDim.x + threadIdx.x;
  int stride = gridDim.x * blockDim.x;
  for (; i < nE; i += stride) {
    int r = row[i];
    unsigned p = atomicAdd(&start[r], 1u);
    colS[p] = col[i];
  }
}

// ---------------- shared compute kernels ------------------------------------
__global__ __launch_bounds__(256) void k_gemm_dual(
    const float* __restrict__ x, const float* __restrict__ W,
    const float* __restrict__ b, const float* __restrict__ Wr,
    const float* __restrict__ br, float* __restrict__ h,
    float* __restrict__ agg, int nNodes, int reluIn)
{
  __shared__ float4 xrow4[4][16];
  const int t = threadIdx.x, wave = t >> 6, lane = t & 63;
  const float4* W4  = (const float4*)W;
  const float4* Wr4 = (const float4*)Wr;
  float4 w4[16], wr4[16];
#pragma unroll
  for (int i = 0; i < 16; ++i) { w4[i] = W4[lane * 16 + i]; wr4[i] = Wr4[lane * 16 + i]; }
  const float bo = b[lane], bro = br[lane];
  float* xs = (float*)&xrow4[wave][0];
  const int gw = blockIdx.x * 4 + wave, nW = gridDim.x * 4;
  for (int n = gw; n < nNodes; n += nW) {
    float xv = x[(size_t)n * 64 + lane];
    if (reluIn) xv = fmaxf(xv, 0.f);
    xs[lane] = xv;
    float ha = bo, aa = bro;
#pragma unroll
    for (int k4 = 0; k4 < 16; ++k4) {
      float4 xk = xrow4[wave][k4];
      ha += xk.x * w4[k4].x + xk.y * w4[k4].y + xk.z * w4[k4].z + xk.w * w4[k4].w;
      aa += xk.x * wr4[k4].x + xk.y * wr4[k4].y + xk.z * wr4[k4].z + xk.w * wr4[k4].w;
    }
    h[(size_t)n * 64 + lane]   = ha;
    agg[(size_t)n * 64 + lane] = aa;
  }
}

__global__ __launch_bounds__(256) void k_spmm(
    const float* __restrict__ h, float* __restrict__ agg,
    const int* __restrict__ colS, const unsigned* __restrict__ startEnd,
    const float* __restrict__ dis, int nNodes)
{
  const int t = threadIdx.x, wave = t >> 6, lane = t & 63;
  const int n = blockIdx.x * 4 + wave;
  if (n >= nNodes) return;
  const unsigned lo = n ? startEnd[n - 1] : 0u;
  const unsigned hi = startEnd[n];
  float m = 0.f;
  for (unsigned base = lo; base < hi; base += 64) {
    const int cnt = (int)min(64u, hi - base);
    int   myc = (lane < cnt) ? colS[base + lane] : 0;
    float myw = (lane < cnt) ? dis[myc] : 0.f;
    int j = 0;
    for (; j + 3 < cnt; j += 4) {
      int c0 = __shfl(myc, j), c1 = __shfl(myc, j + 1);
      int c2 = __shfl(myc, j + 2), c3 = __shfl(myc, j + 3);
      float w0 = __shfl(myw, j), w1 = __shfl(myw, j + 1);
      float w2 = __shfl(myw, j + 2), w3 = __shfl(myw, j + 3);
      float v0 = h[(size_t)c0 * 64 + lane];
      float v1 = h[(size_t)c1 * 64 + lane];
      float v2 = h[(size_t)c2 * 64 + lane];
      float v3 = h[(size_t)c3 * 64 + lane];
      m += w0 * v0; m += w1 * v1; m += w2 * v2; m += w3 * v3;
    }
    for (; j < cnt; ++j) {
      int c = __shfl(myc, j);
      float w = __shfl(myw, j);
      m += w * h[(size_t)c * 64 + lane];
    }
  }
  const size_t o = (size_t)n * 64 + lane;
  agg[o] += dis[n] * m;
}

__global__ __launch_bounds__(256) void k_final(
    const float* __restrict__ agg1, const float* __restrict__ agg2,
    const float* __restrict__ Wl, const float* __restrict__ bl,
    float* __restrict__ out, int nNodes)
{
  __shared__ float4 xrow4[4][32];
  const int t = threadIdx.x, wave = t >> 6, lane = t & 63;
  const int lc = lane < 40 ? lane : 0;
  const float4* Wl4 = (const float4*)Wl;
  float4 wl4[32];
#pragma unroll
  for (int i = 0; i < 32; ++i) wl4[i] = Wl4[lc * 32 + i];
  const float blv = bl[lc];
  float* xs = (float*)&xrow4[wave][0];
  const int gw = blockIdx.x * 4 + wave, nW = gridDim.x * 4;
  for (int n = gw; n < nNodes; n += nW) {
    xs[lane]      = fmaxf(agg1[(size_t)n * 64 + lane], 0.f);
    xs[64 + lane] = fmaxf(agg2[(size_t)n * 64 + lane], 0.f);
    float acc = blv;
#pragma unroll
    for (int k4 = 0; k4 < 32; ++k4) {
      float4 xk = xrow4[wave][k4];
      acc += xk.x * wl4[k4].x + xk.y * wl4[k4].y + xk.z * wl4[k4].z + xk.w * wl4[k4].w;
    }
    float lv = lane < 40 ? acc : -INFINITY;
    float m = lv;
#pragma unroll
    for (int off = 32; off; off >>= 1) m = fmaxf(m, __shfl_xor(m, off));
    float ex = lane < 40 ? __expf(acc - m) : 0.f;
    float s = ex;
#pragma unroll
    for (int off = 32; off; off >>= 1) s += __shfl_xor(s, off);
    if (lane < 40) out[(size_t)n * 40 + lane] = acc - m - __logf(s);
  }
}

extern "C" void kernel_launch(void* const* d_in, const int* in_sizes, int n_in,
                              void* d_out, int out_size, void* d_ws, size_t ws_size,
                              hipStream_t stream) {
  const float* x0  = (const float*)d_in[0];
  const int*   ei  = (const int*)d_in[1];
  const float* W1  = (const float*)d_in[2];
  const float* b1  = (const float*)d_in[3];
  const float* Wr1 = (const float*)d_in[4];
  const float* br1 = (const float*)d_in[5];
  const float* W2  = (const float*)d_in[6];
  const float* b2  = (const float*)d_in[7];
  const float* Wr2 = (const float*)d_in[8];
  const float* br2 = (const float*)d_in[9];
  const float* Wl  = (const float*)d_in[10];
  const float* bl  = (const float*)d_in[11];
  float* out = (float*)d_out;

  const int N = in_sizes[0] / 64;
  const int E = in_sizes[1] / 2;
  const int* row = ei;
  const int* col = ei + E;

  const int NB = (N + BROWS - 1) / BROWS;     // 196
  const int capA = 12288;
  const int avg = E / (NB > 0 ? NB : 1);
  const bool binOK = (N <= 131072) && (NB <= 256) &&
                     (avg + 12 * (int)sqrtf((float)avg + 1.f) + 256 <= capA);

  // binned layout (words): bCnt[256] | bBase[256] | pairs[NB*capA] | colS[E] |
  //                        start[N] | dis[N] | h[64N] | agg1[64N] | agg2[64N]
  const size_t needBin = (size_t)4 * (512 + (size_t)NB * capA + (size_t)E + (size_t)2 * N + (size_t)192 * N);
  const size_t needCSR = (size_t)4 * ((size_t)3 * N + 64 + (size_t)E + (size_t)192 * N);

  if (binOK && ws_size >= needBin) {
    unsigned* bCnt  = (unsigned*)d_ws;
    unsigned* bBase = bCnt + 256;
    unsigned* pairs = bBase + 256;
    int*      colS  = (int*)(pairs + (size_t)NB * capA);
    unsigned* start = (unsigned*)(colS + E);
    float*    dis   = (float*)(start + N);
    float*    h     = dis + N;
    float*    agg1  = h + (size_t)64 * N;
    float*    agg2  = agg1 + (size_t)64 * N;

    hipMemsetAsync(bCnt, 0, 256 * 4, stream);
    k_binA<<<(E + BIN_CHUNK - 1) / BIN_CHUNK, 256, 0, stream>>>(row, col, bCnt, pairs, E, NB, capA);
    k_bscan<<<1, 256, 0, stream>>>(bCnt, bBase, NB, capA);
    k_binB<<<NB, 256, 0, stream>>>(pairs, bCnt, bBase, colS, start, dis, N, capA);

    k_gemm_dual<<<2048, 256, 0, stream>>>(x0, W1, b1, Wr1, br1, h, agg1, N, 0);
    k_spmm<<<(N + 3) / 4, 256, 0, stream>>>(h, agg1, colS, start, dis, N);

    k_gemm_dual<<<2048, 256, 0, stream>>>(agg1, W2, b2, Wr2, br2, h, agg2, N, 1);
    k_spmm<<<(N + 3) / 4, 256, 0, stream>>>(h, agg2, colS, start, dis, N);

    k_final<<<2048, 256, 0, stream>>>(agg1, agg2, Wl, bl, out, N);
  } else if (ws_size >= needCSR) {
    unsigned* deg   = (unsigned*)d_ws;
    unsigned* start = deg + N;
    float*    dis   = (float*)(start + N);
    unsigned* bsum  = (unsigned*)(dis + N);
    int*      colS  = (int*)(bsum + 64);
    float*    h     = (float*)(colS + E);
    float*    agg1  = h + (size_t)64 * N;
    float*    agg2  = agg1 + (size_t)64 * N;

    const int nB = (N + 2047) / 2048;

    hipMemsetAsync(deg, 0, (size_t)N * 4, stream);
    k_deg<<<1024, 256, 0, stream>>>(row, deg, E);
    k_dis<<<(N + 255) / 256, 256, 0, stream>>>(deg, dis, N);
    k_scan1<<<nB, 256, 0, stream>>>(deg, start, bsum, N);
    k_scan2<<<1, 64, 0, stream>>>(bsum, nB);
    k_scan3<<<(N + 255) / 256, 256, 0, stream>>>(start, bsum, N);
    k_build<<<1024, 256, 0, stream>>>(row, col, start, colS, E);

    k_gemm_dual<<<2048, 256, 0, stream>>>(x0, W1, b1, Wr1, br1, h, agg1, N, 0);
    k_spmm<<<(N + 3) / 4, 256, 0, stream>>>(h, agg1, colS, start, dis, N);

    k_gemm_dual<<<2048, 256, 0, stream>>>(agg1, W2, b2, Wr2, br2, h, agg2, N, 1);
    k_spmm<<<(N + 3) / 4, 256, 0, stream>>>(h, agg2, colS, start, dis, N);

    k_final<<<2048, 256, 0, stream>>>(agg1, agg2, Wl, bl, out, N);
  }
}